// Round 1
// baseline (276.904 us; speedup 1.0000x reference)
//
#include <hip/hip_runtime.h>

typedef __attribute__((ext_vector_type(8))) short short8;
typedef __attribute__((ext_vector_type(4))) float floatx4;

#define NROWS 32768L          // padded row count (real pair rows = 32767)
#define NVALID 32767L
#define HGDIM 1024

__device__ __forceinline__ unsigned short f2bf_rne(float f) {
    union { float f; unsigned u; } v; v.f = f;
    unsigned r = v.u + 0x7fffu + ((v.u >> 16) & 1u);
    return (unsigned short)(r >> 16);
}

__device__ __forceinline__ void gload_lds16(const void* g, void* l) {
    __builtin_amdgcn_global_load_lds(
        (const __attribute__((address_space(1))) void*)g,
        (__attribute__((address_space(3))) void*)l,
        16, 0, 0);
}

// ---- convert x (fp32) -> bf16, zero-padding one extra row ----
__global__ void cvt_x(const float* __restrict__ x, unsigned short* __restrict__ xb,
                      long nx, long ntot4) {
    long i = (long)blockIdx.x * 256 + threadIdx.x;
    if (i >= ntot4) return;
    long i4 = i * 4;
    float4 v = make_float4(0.f, 0.f, 0.f, 0.f);
    if (i4 < nx) v = *(const float4*)(x + i4);
    ushort4 o;
    o.x = f2bf_rne(v.x); o.y = f2bf_rne(v.y); o.z = f2bf_rne(v.z); o.w = f2bf_rne(v.w);
    *(ushort4*)(xb + i4) = o;
}

// ---- W (K x N, fp32, row-major) -> Wt (N x K, bf16, row-major) ----
__global__ void transpose_cvt(const float* __restrict__ W, unsigned short* __restrict__ Wt,
                              int K, int N) {
    __shared__ float tile[32][33];
    int tx = threadIdx.x & 31, ty = threadIdx.x >> 5;   // 32 x 8
    int nb = blockIdx.x * 32, kb = blockIdx.y * 32;
    #pragma unroll
    for (int i = 0; i < 32; i += 8)
        tile[ty + i][tx] = W[(size_t)(kb + ty + i) * N + (nb + tx)];
    __syncthreads();
    #pragma unroll
    for (int i = 0; i < 32; i += 8)
        Wt[(size_t)(nb + ty + i) * K + (kb + tx)] = f2bf_rne(tile[tx][ty + i]);
}

// ---- small fp32 FC partial:  out[j] += sum_{k in slice} act(in[k]) * W[k*N+j]  (+bias if ky==0)
template<bool RELU_IN>
__global__ void fc_partial(const float* __restrict__ in, const float* __restrict__ W,
                           const float* __restrict__ bias, float* __restrict__ out,
                           int N) {
    __shared__ float s_in[128];
    int j = blockIdx.x * 256 + threadIdx.x;
    int k0 = blockIdx.y * 128;
    if (threadIdx.x < 128) {
        float v = in[k0 + threadIdx.x];
        if (RELU_IN) v = fmaxf(v, 0.f);
        s_in[threadIdx.x] = v;
    }
    __syncthreads();
    float acc = (blockIdx.y == 0) ? bias[j] : 0.f;
    #pragma unroll 4
    for (int k = 0; k < 128; ++k)
        acc += s_in[k] * W[(size_t)(k0 + k) * N + j];
    atomicAdd(&out[j], acc);
}

// ---- main bf16 MFMA GEMM: C(m,n) = A(m x K) * Bt(n x K)^T, epilogue bias+relu ----
// COLSUM=0: write H (bf16, ld=1024).  COLSUM=1: masked column-sum atomicAdd into emb.
template<int COLSUM>
__global__ __launch_bounds__(256, 2)
void gemm_bt(const unsigned short* __restrict__ A, int lda,
             const unsigned short* __restrict__ Bt, int ldb,
             const float* __restrict__ bias, int K,
             unsigned short* __restrict__ Hout,
             float* __restrict__ emb, long row0g, long nvalid) {
    __shared__ alignas(16) unsigned short ldsA[128 * 64];
    __shared__ alignas(16) unsigned short ldsB[128 * 64];

    const int t = threadIdx.x;
    const int lane = t & 63;
    const int wave = t >> 6;
    const int wm = wave >> 1, wn = wave & 1;
    const int m0 = blockIdx.x * 128;
    const int n0 = blockIdx.y * 128;

    floatx4 acc[4][4] = {};

    const int sr = t >> 3;       // staging row 0..31
    const int spc = t & 7;       // staging 16B-chunk slot 0..7

    for (int k0 = 0; k0 < K; k0 += 64) {
        // stage A and Bt tiles: LDS linear dest, XOR-pre-swizzled global source (guide rule 21)
        #pragma unroll
        for (int i = 0; i < 4; ++i) {
            int rr = sr + 32 * i;
            int pca = spc ^ (rr & 7);
            const unsigned short* gA = A + (size_t)(m0 + rr) * lda + (k0 + pca * 8);
            gload_lds16(gA, (char*)ldsA + (rr * 128 + spc * 16));
            const unsigned short* gB = Bt + (size_t)(n0 + rr) * ldb + (k0 + pca * 8);
            gload_lds16(gB, (char*)ldsB + (rr * 128 + spc * 16));
        }
        asm volatile("s_waitcnt vmcnt(0)" ::: "memory");
        __syncthreads();

        #pragma unroll
        for (int kk = 0; kk < 2; ++kk) {
            short8 af[4], bf[4];
            #pragma unroll
            for (int mf = 0; mf < 4; ++mf) {
                int r = wm * 64 + mf * 16 + (lane & 15);
                int c = kk * 4 + (lane >> 4);
                int pc = c ^ (r & 7);
                af[mf] = *(const short8*)((const char*)ldsA + (r * 128 + pc * 16));
            }
            #pragma unroll
            for (int nf = 0; nf < 4; ++nf) {
                int r = wn * 64 + nf * 16 + (lane & 15);
                int c = kk * 4 + (lane >> 4);
                int pc = c ^ (r & 7);
                bf[nf] = *(const short8*)((const char*)ldsB + (r * 128 + pc * 16));
            }
            #pragma unroll
            for (int mf = 0; mf < 4; ++mf)
                #pragma unroll
                for (int nf = 0; nf < 4; ++nf)
                    acc[mf][nf] = __builtin_amdgcn_mfma_f32_16x16x32_bf16(
                        af[mf], bf[nf], acc[mf][nf], 0, 0, 0);
        }
        __syncthreads();
    }

    // epilogue: C/D layout col = lane&15, row = (lane>>4)*4 + j  [guide m89]
    if (COLSUM == 0) {
        #pragma unroll
        for (int nf = 0; nf < 4; ++nf) {
            int ncol = n0 + wn * 64 + nf * 16 + (lane & 15);
            float bv = bias[ncol];
            #pragma unroll
            for (int mf = 0; mf < 4; ++mf) {
                int rbase = m0 + wm * 64 + mf * 16 + (lane >> 4) * 4;
                #pragma unroll
                for (int j = 0; j < 4; ++j) {
                    float v = fmaxf(acc[mf][nf][j] + bv, 0.f);
                    Hout[(size_t)(rbase + j) * HGDIM + ncol] = f2bf_rne(v);
                }
            }
        }
    } else {
        #pragma unroll
        for (int nf = 0; nf < 4; ++nf) {
            int ncol = n0 + wn * 64 + nf * 16 + (lane & 15);
            float bv = bias[ncol];
            float cs = 0.f;
            #pragma unroll
            for (int mf = 0; mf < 4; ++mf) {
                long rbase = row0g + m0 + wm * 64 + mf * 16 + (lane >> 4) * 4;
                #pragma unroll
                for (int j = 0; j < 4; ++j) {
                    float v = fmaxf(acc[mf][nf][j] + bv, 0.f);
                    if (rbase + j < nvalid) cs += v;
                }
            }
            cs += __shfl_xor(cs, 16);
            cs += __shfl_xor(cs, 32);
            if ((lane >> 4) == 0) atomicAdd(&emb[ncol], cs);
        }
    }
}

extern "C" void kernel_launch(void* const* d_in, const int* in_sizes, int n_in,
                              void* d_out, int out_size, void* d_ws, size_t ws_size,
                              hipStream_t stream) {
    const float* x   = (const float*)d_in[0];
    const float* q   = (const float*)d_in[1];
    const float* gW0 = (const float*)d_in[2];
    const float* gb0 = (const float*)d_in[3];
    const float* gW1 = (const float*)d_in[4];
    const float* gb1 = (const float*)d_in[5];
    const float* gW2 = (const float*)d_in[6];
    const float* gb2 = (const float*)d_in[7];
    const float* fW0 = (const float*)d_in[8];
    const float* fb0 = (const float*)d_in[9];
    const float* fW1 = (const float*)d_in[10];
    const float* fb1 = (const float*)d_in[11];
    const float* fW2 = (const float*)d_in[12];
    const float* fb2 = (const float*)d_in[13];
    float* out = (float*)d_out;

    char* ws = (char*)d_ws;
    size_t off = 0;
    auto alloc = [&](size_t bytes) -> char* {
        char* p = ws + off;
        off += (bytes + 255) & ~(size_t)255;
        return p;
    };
    unsigned short* xb  = (unsigned short*)alloc((NROWS + 1) * 256 * 2);  // +1 zero row
    unsigned short* w0t = (unsigned short*)alloc((size_t)1024 * 512 * 2);
    unsigned short* w1t = (unsigned short*)alloc((size_t)1024 * 1024 * 2);
    unsigned short* w2t = (unsigned short*)alloc((size_t)1024 * 1024 * 2);
    float* c0  = (float*)alloc(4096);
    float* emb = (float*)alloc(4096);
    float* e1  = (float*)alloc(4096);
    float* e2  = (float*)alloc(4096);
    size_t fixed = off;
    size_t avail = (ws_size > fixed) ? ws_size - fixed : 0;
    long CR = (long)((avail / 2) / (HGDIM * 2));
    CR = (CR / 128) * 128;
    if (CR > NROWS) CR = NROWS;
    if (CR < 128) CR = 128;
    unsigned short* H0 = (unsigned short*)alloc((size_t)CR * HGDIM * 2);
    unsigned short* H1 = (unsigned short*)alloc((size_t)CR * HGDIM * 2);

    // zero the small accumulators (c0, emb, e1, e2 are contiguous) and d_out
    hipMemsetAsync(c0, 0, 4 * 4096, stream);
    hipMemsetAsync(out, 0, 256 * sizeof(float), stream);

    // x -> bf16 (+ zero pad row)
    long ntot4 = (NROWS + 1) * 256 / 4;
    cvt_x<<<dim3((unsigned)((ntot4 + 255) / 256)), 256, 0, stream>>>(x, xb, NROWS * 256, ntot4);

    // weight transposes to bf16 [N][K]
    transpose_cvt<<<dim3(32, 16), 256, 0, stream>>>(gW0, w0t, 512, 1024);
    transpose_cvt<<<dim3(32, 32), 256, 0, stream>>>(gW1, w1t, 1024, 1024);
    transpose_cvt<<<dim3(32, 32), 256, 0, stream>>>(gW2, w2t, 1024, 1024);

    // c0 = q @ W0[512:768] + b0  (fp32)
    fc_partial<false><<<dim3(4, 2), 256, 0, stream>>>(q, gW0 + (size_t)512 * 1024, gb0, c0, 1024);

    // main pipeline, chunked by workspace size
    for (long r0 = 0; r0 < NROWS; r0 += CR) {
        long rows = NROWS - r0; if (rows > CR) rows = CR;
        dim3 g((unsigned)(rows / 128), 8);
        // H0 = relu(x[:-1]*W0a + x[1:]*W0b + c0): A rows are overlapping 512-windows of xb
        gemm_bt<0><<<g, 256, 0, stream>>>(xb + r0 * 256, 256, w0t, 512, c0, 512,
                                          H0, nullptr, 0, 0);
        // H1 = relu(H0 @ W1 + b1)
        gemm_bt<0><<<g, 256, 0, stream>>>(H0, 1024, w1t, 1024, gb1, 1024,
                                          H1, nullptr, 0, 0);
        // emb += colsum(relu(H1 @ W2 + b2)), masking the padded row
        gemm_bt<1><<<g, 256, 0, stream>>>(H1, 1024, w2t, 1024, gb2, 1024,
                                          nullptr, emb, r0, NVALID);
    }

    // f-MLP (fp32): relu deferred to next layer's read
    fc_partial<false><<<dim3(4, 8), 256, 0, stream>>>(emb, fW0, fb0, e1, 1024);
    fc_partial<true><<<dim3(2, 8), 256, 0, stream>>>(e1, fW1, fb1, e2, 512);
    fc_partial<true><<<dim3(1, 4), 256, 0, stream>>>(e2, fW2, fb2, out, 256);
}